// Round 2
// baseline (663.792 us; speedup 1.0000x reference)
//
#include <hip/hip_runtime.h>

#define KK 27
#define INC 32
#define PC 64

typedef __attribute__((ext_vector_type(8))) short v8s;
typedef __attribute__((ext_vector_type(4))) float f32x4;

static __device__ __forceinline__ float b2f(ushort u) {
  union { float f; unsigned int i; } x; x.i = ((unsigned int)u) << 16; return x.f;
}
static __device__ __forceinline__ ushort f2b(float f) {
  union { float f; unsigned int i; } x; x.f = f;
  unsigned int u = x.i;
  unsigned int r = (u + 0x7FFFu + ((u >> 16) & 1u)) >> 16;
  return (ushort)r;
}

// ---------------- Kernel 1: x = relu(xf@Wt+bt) [bf16], v = relu(x@Wv+bv) [bf16]
__global__ __launch_bounds__(256) void k_prep(
    const float* __restrict__ xf, const float* __restrict__ Wt, const float* __restrict__ bt,
    const float* __restrict__ Wv, const float* __restrict__ bv,
    ushort* __restrict__ x, ushort* __restrict__ v, int N)
{
  int lane = threadIdx.x & 63, w = threadIdx.x >> 6;
  int n = blockIdx.x * 4 + w;
  bool valid = n < N;
  __shared__ float xin_s[4][32];
  __shared__ float xs[4][64];
  if (valid && lane < 32) xin_s[w][lane] = xf[n * INC + lane];
  __syncthreads();
  float ax = 0.f;
  if (valid) {
    ax = bt[lane];
    #pragma unroll
    for (int i = 0; i < INC; ++i) ax += xin_s[w][i] * Wt[i * PC + lane];
    ax = fmaxf(ax, 0.f);
    xs[w][lane] = ax;
  }
  __syncthreads();
  if (valid) {
    x[n * PC + lane] = f2b(ax);
    float av = bv[lane];
    #pragma unroll
    for (int i = 0; i < PC; ++i) av += xs[w][i] * Wv[i * PC + lane];
    v[n * PC + lane] = f2b(fmaxf(av, 0.f));
  }
}

// ---------------- Kernel 2: q + softmax attn (one wave per voxel)
__global__ __launch_bounds__(256) void k_attn(
    const ushort* __restrict__ x, const int* __restrict__ nbr_idx, const int* __restrict__ nbr_mask,
    const int* __restrict__ coords,
    const float* __restrict__ Wpos, const float* __restrict__ bpos,
    const float* __restrict__ Wq, const float* __restrict__ bq,
    const float* __restrict__ proj, float* __restrict__ attn, int N)
{
  int lane = threadIdx.x & 63, w = threadIdx.x >> 6;
  int n = blockIdx.x * 4 + w;
  if (n >= N) return;
  float wp0 = Wpos[lane], wp1 = Wpos[64 + lane], wp2 = Wpos[128 + lane];
  float bp = bpos[lane];
  int cx = coords[n * 3 + 0], cy = coords[n * 3 + 1], cz = coords[n * 3 + 2];
  float qacc = 0.f;
  for (int k = 0; k < KK; ++k) {
    int msk = nbr_mask[n * KK + k];
    if (msk) {
      int j = nbr_idx[n * KK + k];
      float rx = (float)(coords[j * 3 + 0] - cx);
      float ry = (float)(coords[j * 3 + 1] - cy);
      float rz = (float)(coords[j * 3 + 2] - cz);
      float pos = fmaxf(rx * wp0 + ry * wp1 + rz * wp2 + bp, 0.f);
      float val = b2f(x[j * PC + lane]) + pos;
      qacc += val * Wq[k * PC + lane];
    }
  }
  #pragma unroll
  for (int off = 32; off > 0; off >>= 1) qacc += __shfl_xor(qacc, off);
  float q = fmaxf(qacc + bq[0], 0.f);
  if (lane == 0) {
    float l[4], mx = -1e30f;
    #pragma unroll
    for (int m = 0; m < 4; ++m) { l[m] = q * proj[m] * 0.1f; mx = fmaxf(mx, l[m]); }
    float s = 0.f;
    #pragma unroll
    for (int m = 0; m < 4; ++m) { l[m] = __expf(l[m] - mx); s += l[m]; }
    float inv = 1.f / s;
    #pragma unroll
    for (int m = 0; m < 4; ++m) attn[n * 4 + m] = l[m] * inv;
  }
}

// ---------------- Kernel 3: repack W_code f32 [m,k,c,d] -> bf16 Bp[s][kg][col][j], k=s*32+kg*8+j, col=m*64+d
__global__ __launch_bounds__(256) void k_prepB(const float* __restrict__ Wcode, ushort* __restrict__ Bp)
{
  int i = blockIdx.x * 256 + threadIdx.x;   // 54*4*256*8 = 442368 total, exact multiple of 256
  int j = i & 7;
  int col = (i >> 3) & 255;
  int kg = (i >> 11) & 3;
  int s = i >> 13;
  int k = s * 32 + kg * 8 + j;
  int m = col >> 6, d = col & 63;
  int knbr = k >> 6, c = k & 63;
  Bp[i] = f2b(Wcode[(((m * KK + knbr) * 64) + c) * 64 + d]);
}

// ---------------- Kernel 4: gathered GEMM [64 x 1728] x [1728 x 256] + attn/residual epilogue
__global__ __launch_bounds__(256) void k_code(
    const ushort* __restrict__ v, const int* __restrict__ nbr_idx, const int* __restrict__ nbr_mask,
    const ushort* __restrict__ Bp, const float* __restrict__ attn,
    const float* __restrict__ xf, const float* __restrict__ Wd, const float* __restrict__ bd,
    const float* __restrict__ bcode, float* __restrict__ out, int N)
{
  const int tid = threadIdx.x;
  const int lane = tid & 63, wv_ = tid >> 6;
  const int base = blockIdx.x * 64;
  __shared__ __align__(16) ushort As[64 * 64];   // XOR-swizzled A tile
  __shared__ float outs[64 * 64];
  __shared__ float xfs[64 * 32];

  f32x4 acc[4][4] = {};

  for (int kn = 0; kn < KK; ++kn) {
    __syncthreads();
    // stage gathered+masked v rows: 64 rows x 64ch, 16B chunks
    for (int ch = tid; ch < 512; ch += 256) {
      int r = ch >> 3, cc = ch & 7;
      int n = base + r;
      uint4 data = make_uint4(0u, 0u, 0u, 0u);
      if (n < N) {
        int msk = nbr_mask[n * KK + kn];
        if (msk) {
          int j = nbr_idx[n * KK + kn];
          data = *(const uint4*)(v + j * PC + cc * 8);
        }
      }
      int sc = cc ^ (r & 7);
      *(uint4*)(As + r * 64 + sc * 8) = data;
    }
    __syncthreads();
    #pragma unroll
    for (int s2 = 0; s2 < 2; ++s2) {
      int s = kn * 2 + s2;
      v8s bf[4], af[4];
      const ushort* bb = Bp + (size_t)(s * 4 + (lane >> 4)) * 2048;
      #pragma unroll
      for (int nt = 0; nt < 4; ++nt) {
        int col = wv_ * 64 + nt * 16 + (lane & 15);
        bf[nt] = *(const v8s*)(bb + col * 8);
      }
      #pragma unroll
      for (int mt = 0; mt < 4; ++mt) {
        int r = mt * 16 + (lane & 15);
        int cc = s2 * 4 + (lane >> 4);
        int sc = cc ^ (r & 7);
        af[mt] = *(const v8s*)(As + r * 64 + sc * 8);
      }
      #pragma unroll
      for (int mt = 0; mt < 4; ++mt)
        #pragma unroll
        for (int nt = 0; nt < 4; ++nt)
          acc[mt][nt] = __builtin_amdgcn_mfma_f32_16x16x32_bf16(af[mt], bf[nt], acc[mt][nt], 0, 0, 0);
    }
  }

  // epilogue: out[n,d] = relu( sum_m attn[n,m]*relu(code[n,m,d]+bc) + (xf@Wd+bd) )
  __syncthreads();
  for (int i2 = tid; i2 < 4096; i2 += 256) outs[i2] = 0.f;
  for (int i2 = tid; i2 < 2048; i2 += 256) {
    int r = i2 >> 5, c = i2 & 31;
    int n = base + r;
    xfs[i2] = (n < N) ? xf[n * INC + c] : 0.f;
  }
  __syncthreads();
  for (int t = 0; t < 4; ++t) {
    if (wv_ == t) {
      #pragma unroll
      for (int mt = 0; mt < 4; ++mt)
        #pragma unroll
        for (int nt = 0; nt < 4; ++nt) {
          int d = nt * 16 + (lane & 15);
          float bcv = bcode[wv_ * 64 + d];
          #pragma unroll
          for (int i = 0; i < 4; ++i) {
            int r = mt * 16 + (lane >> 4) * 4 + i;
            int n = base + r;
            if (n < N) {
              float code = fmaxf(acc[mt][nt][i] + bcv, 0.f);
              outs[r * 64 + d] += attn[n * 4 + wv_] * code;
            }
          }
        }
    }
    __syncthreads();
  }
  for (int i2 = tid; i2 < 4096; i2 += 256) {
    int r = i2 >> 6, d = i2 & 63;
    int n = base + r;
    if (n < N) {
      float racc = bd[d];
      #pragma unroll
      for (int c = 0; c < INC; ++c) racc += xfs[r * 32 + c] * Wd[c * PC + d];
      out[n * PC + d] = fmaxf(outs[i2] + racc, 0.f);
    }
  }
}

extern "C" void kernel_launch(void* const* d_in, const int* in_sizes, int n_in,
                              void* d_out, int out_size, void* d_ws, size_t ws_size,
                              hipStream_t stream)
{
  const float* xf     = (const float*)d_in[0];
  const int* nbr_idx  = (const int*)d_in[1];
  const int* nbr_mask = (const int*)d_in[2];
  const int* coords   = (const int*)d_in[3];
  const float* Wt     = (const float*)d_in[4];
  const float* bt     = (const float*)d_in[5];
  const float* Wd     = (const float*)d_in[6];
  const float* bd     = (const float*)d_in[7];
  const float* Wpos   = (const float*)d_in[8];
  const float* bpos   = (const float*)d_in[9];
  const float* Wq     = (const float*)d_in[10];
  const float* bq     = (const float*)d_in[11];
  const float* proj   = (const float*)d_in[12];
  const float* Wv     = (const float*)d_in[13];
  const float* bv     = (const float*)d_in[14];
  const float* Wcode  = (const float*)d_in[15];
  const float* bcode  = (const float*)d_in[16];
  float* out = (float*)d_out;

  int N = in_sizes[0] / INC;

  char* ws = (char*)d_ws;
  size_t off = 0;
  auto alloc = [&](size_t bytes) {
    off = (off + 255) & ~(size_t)255;
    void* p = ws + off;
    off += bytes;
    return p;
  };
  ushort* x_ws = (ushort*)alloc((size_t)N * PC * 2);
  ushort* v_ws = (ushort*)alloc((size_t)N * PC * 2);
  float*  a_ws = (float*)alloc((size_t)N * 4 * 4);
  ushort* B_ws = (ushort*)alloc((size_t)54 * 4 * 256 * 8 * 2);
  (void)ws_size;

  int nb4 = (N + 3) / 4;
  hipLaunchKernelGGL(k_prep, dim3(nb4), dim3(256), 0, stream,
                     xf, Wt, bt, Wv, bv, x_ws, v_ws, N);
  hipLaunchKernelGGL(k_attn, dim3(nb4), dim3(256), 0, stream,
                     x_ws, nbr_idx, nbr_mask, coords, Wpos, bpos, Wq, bq, proj, a_ws, N);
  hipLaunchKernelGGL(k_prepB, dim3((54 * 4 * 256 * 8) / 256), dim3(256), 0, stream,
                     Wcode, B_ws);
  hipLaunchKernelGGL(k_code, dim3((N + 63) / 64), dim3(256), 0, stream,
                     v_ws, nbr_idx, nbr_mask, B_ws, a_ws, xf, Wd, bd, bcode, out, N);
}